// Round 11
// baseline (26.129 us; speedup 1.0000x reference)
//
#include <hip/hip_runtime.h>

#define NN 512
typedef unsigned long long u64;

// ---------- k1: per-row (one wave): m-mask -> keep1 (own-filtered) + scatter
// remove-bits into transposed mask rmT (rmT[i] bit j == remove(j,i)).
__global__ __launch_bounds__(64, 1) void k_remove(const float* __restrict__ adj,
                                                  u64* __restrict__ keep1,
                                                  u64* __restrict__ rmT) {
    int lane = threadIdx.x;
    int r = blockIdx.x;                 // b*N + i
    int b = r >> 9, i = r & (NN - 1);
    const float* row = adj + (size_t)r * NN;

    u64 mw[8];
    #pragma unroll
    for (int q = 0; q < 8; ++q) {
        int j = q * 64 + lane;
        mw[q] = __ballot((j != i) && (row[j] > 0.0f));
    }
    int num = 0;
    #pragma unroll
    for (int q = 0; q < 8; ++q) num += __popcll(mw[q]);
    int skip = (num > 10) ? ((num + 1) >> 1) : 1;   // T_THRESH=10, K_DIL=2

    u64 lm = (1ULL << lane) - 1ULL;
    int iw = i >> 6; u64 ib = 1ULL << (i & 63);
    u64 kw = 0;
    int pre = 0;
    #pragma unroll
    for (int q = 0; q < 8; ++q) {
        bool m = (mw[q] >> lane) & 1ULL;
        int rel = pre + __popcll(mw[q] & lm);       // rank among m-entries
        bool rem = m && (skip > 1) && (rel % skip == skip - 1);
        u64 rb = __ballot(rem);
        if (lane == q) kw = mw[q] & ~rb;            // static per-lane slot
        // scatter: remove(i, j=q*64+lane) -> rmT[j] bit i  (~2 lanes active/row)
        if (rem)
            atomicOr(&rmT[((size_t)(b * NN + q * 64 + lane)) * 8 + iw], ib);
        pre += __popcll(mw[q]);
    }
    if (lane < 8) keep1[(size_t)r * 8 + lane] = kw;
}

// ---------- in-register bitonic sorting network (compile-time indices) ----------
template<int NS>
__device__ __forceinline__ void sort_net(float* v) {
    #pragma unroll
    for (int k = 2; k <= NS; k <<= 1) {
        #pragma unroll
        for (int j = k >> 1; j > 0; j >>= 1) {
            #pragma unroll
            for (int i = 0; i < NS; ++i) {
                int ixj = i ^ j;
                if (ixj > i) {
                    float a = v[i], c = v[ixj];
                    float mn = fminf(a, c), mx = fmaxf(a, c);
                    if ((i & k) == 0) { v[i] = mn; v[ixj] = mx; }
                    else              { v[i] = mx; v[ixj] = mn; }
                }
            }
        }
    }
}

// gather ct final neighbors (+inf pad), sort, emit window rows [kmin..kmax]
template<int NS>
__device__ __forceinline__ void gather_sort_win(const float* __restrict__ xb,
                                                const int* jl, int ct,
                                                float* win, int lane,
                                                int kmin, int kmax) {
    float v[NS];
    #pragma unroll
    for (int a = 0; a < NS; ++a) {
        v[a] = (a < ct) ? xb[(size_t)jl[a] * 64 + lane]   // uniform branch, coalesced 256B
                        : __builtin_inff();               // pad (matches ref +inf)
    }
    sort_net<NS>(v);
    #pragma unroll
    for (int a = 0; a < NS; ++a)
        if (a >= kmin && a <= kmax)                       // uniform: only window written
            win[(a - kmin) * 64 + lane] = v[a];
}

// ---------- k2: per-row (one wave): final mask via keep1 & ~rmT, quantiles, GEMV ----------
__global__ __launch_bounds__(64, 2) void k_quant(const float* __restrict__ x,
                                                 const float* __restrict__ Wl,
                                                 const float* __restrict__ bl,
                                                 const float* __restrict__ Wr,
                                                 const u64* __restrict__ keep1,
                                                 const u64* __restrict__ rmT,
                                                 float* __restrict__ out) {
    __shared__ float win[34 * 64];      // quantile window (max width 34); reused for GEMV bcast
    __shared__ int   jl[72];            // final neighbor list + self (fast path)
    __shared__ int   jls[NN];           // slow-path list (statistically unreachable)
    int lane = threadIdx.x;
    int r = blockIdx.x;
    int b = r >> 9, i = r & (NN - 1);
    const float* xb = x + (size_t)b * NN * 64;

    // final neighbor mask: 8+8 coalesced u64 loads, zero scattered traffic
    u64 nb[8];
    #pragma unroll
    for (int q = 0; q < 8; ++q)
        nb[q] = keep1[(size_t)r * 8 + q] & ~rmT[(size_t)r * 8 + q];

    // rank-select final neighbor list
    u64 lm = (1ULL << lane) - 1ULL;
    int pre = 0;
    #pragma unroll
    for (int q = 0; q < 8; ++q) {
        if ((nb[q] >> lane) & 1ULL) {
            int rank = pre + __popcll(nb[q] & lm);
            if (rank < 71) jl[rank] = q * 64 + lane;
        }
        pre += __popcll(nb[q]);
    }
    int degm = pre;                     // neighbors excluding self
    if (lane == 0 && degm < 71) jl[degm] = i;   // self always a neighbor
    __syncthreads();
    int deg = degm + 1;

    float xi = xb[(size_t)i * 64 + lane];

    // quantile rank constants (f32 math identical to reference)
    float pm = fmaxf((float)deg - 1.0f, 0.0f);
    float pos0 = 0.25f * pm, pos1 = 0.5f * pm, pos2 = 0.75f * pm;
    float l0 = floorf(pos0), l1 = floorf(pos1), l2 = floorf(pos2);
    float fr0 = pos0 - l0, fr1 = pos1 - l1, fr2 = pos2 - l2;
    int kks[6] = {(int)l0, (int)ceilf(pos0), (int)l1, (int)ceilf(pos1),
                  (int)l2, (int)ceilf(pos2)};

    float qv[6];
    if (deg <= 64) {
        int kmin = kks[0], kmax = kks[5];       // width <= 34 for deg <= 64
        if (deg <= 32) gather_sort_win<32>(xb, jl, deg, win, lane, kmin, kmax);
        else           gather_sort_win<64>(xb, jl, deg, win, lane, kmin, kmax);
        __syncthreads();
        #pragma unroll
        for (int q = 0; q < 6; ++q) qv[q] = win[(kks[q] - kmin) * 64 + lane];
    } else {
        // slow safe path: full list + O(deg^2) rank count on global reads
        int pre2 = 0;
        #pragma unroll
        for (int q = 0; q < 8; ++q) {
            if ((nb[q] >> lane) & 1ULL)
                jls[pre2 + __popcll(nb[q] & lm)] = q * 64 + lane;
            pre2 += __popcll(nb[q]);
        }
        if (lane == 0) jls[pre2] = i;
        __syncthreads();
        for (int a2 = 0; a2 < deg; ++a2) {
            float v1 = xb[(size_t)jls[a2] * 64 + lane];
            int cl = 0, ce = 0;
            for (int c = 0; c < deg; ++c) {
                float u = xb[(size_t)jls[c] * 64 + lane];
                cl += (u < v1); ce += (u == v1);
            }
            #pragma unroll
            for (int q = 0; q < 6; ++q)
                if (cl <= kks[q] && kks[q] < cl + ce) qv[q] = v1;
        }
    }

    float agg = 0.25f * (qv[0] * (1.0f - fr0) + qv[1] * fr0)
              + 0.50f * (qv[2] * (1.0f - fr1) + qv[3] * fr1)
              + 0.25f * (qv[4] * (1.0f - fr2) + qv[5] * fr2);

    // GEMV: o_f = b_f + sum_k agg_k*Wl[k,f] + xi_k*Wr[k,f]
    __syncthreads();                    // qv reads done before win overwrite
    win[lane] = agg;
    win[64 + lane] = xi;
    __syncthreads();
    float o = bl[lane];
    #pragma unroll
    for (int k = 0; k < 64; ++k)
        o += win[k] * Wl[k * 64 + lane] + win[64 + k] * Wr[k * 64 + lane];

    float ss = o * o;
    #pragma unroll
    for (int off = 32; off >= 1; off >>= 1) ss += __shfl_xor(ss, off);
    out[(size_t)r * 64 + lane] = o / fmaxf(sqrtf(ss), 1e-12f);
}

extern "C" void kernel_launch(void* const* d_in, const int* in_sizes, int n_in,
                              void* d_out, int out_size, void* d_ws, size_t ws_size,
                              hipStream_t stream) {
    const float* x   = (const float*)d_in[0];
    const float* adj = (const float*)d_in[1];
    const float* Wl  = (const float*)d_in[2];
    const float* bl  = (const float*)d_in[3];
    const float* Wr  = (const float*)d_in[4];
    float* out = (float*)d_out;

    int B = in_sizes[0] / (NN * 64);            // 4
    u64* keep1 = (u64*)d_ws;                     // B*N*8 u64 = 128 KB
    u64* rmT   = keep1 + (size_t)B * NN * 8;     // B*N*8 u64 = 128 KB

    // rmT is accumulated via atomicOr -> must start at zero every call
    hipMemsetAsync(rmT, 0, (size_t)B * NN * 8 * sizeof(u64), stream);
    k_remove<<<dim3(B * NN), dim3(64), 0, stream>>>(adj, keep1, rmT);
    k_quant <<<dim3(B * NN), dim3(64), 0, stream>>>(x, Wl, bl, Wr, keep1, rmT, out);
}

// Round 12
// 23.084 us; speedup vs baseline: 1.1319x; 1.1319x over previous
//
#include <hip/hip_runtime.h>

#define NN 512
typedef unsigned long long u64;

// ---------- k1: per-row (one wave): remove mask + ready-made candidate list ----------
// jlist row layout (64 ints): [a] = candidate a (ascending j) for a < ct1,
// [ct1] = self (i), [63] = ct1. If ct1 >= 63 the list is partial and k2 takes
// the slow path (recomputes from adj + rm).
__global__ __launch_bounds__(64, 2) void k_prep(const float* __restrict__ adj,
                                                u64* __restrict__ rm,
                                                int* __restrict__ jlist) {
    int lane = threadIdx.x;
    int r = blockIdx.x;                 // b*N + i
    int i = r & (NN - 1);
    const float* row = adj + (size_t)r * NN;

    u64 mw[8];
    #pragma unroll
    for (int q = 0; q < 8; ++q) {
        int j = q * 64 + lane;
        mw[q] = __ballot((j != i) && (row[j] > 0.0f));
    }
    int num = 0;
    #pragma unroll
    for (int q = 0; q < 8; ++q) num += __popcll(mw[q]);
    int skip = (num > 10) ? ((num + 1) >> 1) : 1;   // T_THRESH=10, K_DIL=2

    u64 lm = (1ULL << lane) - 1ULL;
    u64 rw = 0;
    int pre = 0, ct1 = 0;
    #pragma unroll
    for (int q = 0; q < 8; ++q) {
        bool m = (mw[q] >> lane) & 1ULL;
        int rel = pre + __popcll(mw[q] & lm);       // rank among m-entries
        bool rem = m && (skip > 1) && (rel % skip == skip - 1);
        u64 rb = __ballot(rem);
        if (lane == q) rw = rb;                     // static per-lane slot
        pre += __popcll(mw[q]);
        u64 kb = mw[q] & ~rb;                       // kept candidates this word
        if ((kb >> lane) & 1ULL) {
            int rank = ct1 + __popcll(kb & lm);
            if (rank < 62) jlist[r * 64 + rank] = q * 64 + lane;
        }
        ct1 += __popcll(kb);
    }
    if (lane < 8) rm[(size_t)r * 8 + lane] = rw;
    if (lane == 0) {
        if (ct1 < 63) jlist[r * 64 + ct1] = i;      // append self
        jlist[r * 64 + 63] = ct1;
    }
}

// ---------- in-register bitonic sorting network (compile-time indices) ----------
template<int NS>
__device__ __forceinline__ void sort_net(float* v) {
    #pragma unroll
    for (int k = 2; k <= NS; k <<= 1) {
        #pragma unroll
        for (int j = k >> 1; j > 0; j >>= 1) {
            #pragma unroll
            for (int i = 0; i < NS; ++i) {
                int ixj = i ^ j;
                if (ixj > i) {
                    float a = v[i], c = v[ixj];
                    float mn = fminf(a, c), mx = fmaxf(a, c);
                    if ((i & k) == 0) { v[i] = mn; v[ixj] = mx; }
                    else              { v[i] = mx; v[ixj] = mn; }
                }
            }
        }
    }
}

// issue ALL gather loads (no km dependency -> overlaps the rm epoch)
template<int NS>
__device__ __forceinline__ void gather_v(const float* __restrict__ xb,
                                         int slot, int ct, float* v, int lane) {
    #pragma unroll
    for (int a = 0; a < NS; ++a) {
        int ja = __builtin_amdgcn_readlane(slot, a);      // candidate a's index (uniform)
        v[a] = (a < ct) ? xb[(size_t)ja * 64 + lane]      // coalesced 256B row
                        : __builtin_inff();
    }
}

// mask removed (bit a of km clear) -> +inf, sort, emit window rows [kmin..kmax]
template<int NS>
__device__ __forceinline__ void mask_sort_win(float* v, u64 km, float* win,
                                              int lane, int kmin, int kmax) {
    #pragma unroll
    for (int a = 0; a < NS; ++a)
        if (!((km >> a) & 1ULL)) v[a] = __builtin_inff(); // removed -> +inf (ref pad)
    sort_net<NS>(v);
    #pragma unroll
    for (int a = 0; a < NS; ++a)
        if (a >= kmin && a <= kmax)                       // uniform: window only
            win[(a - kmin) * 64 + lane] = v[a];
}

// ---------- k2: per-row (one wave): 3-epoch chain, quantiles, GEMV, L2-norm ----------
__global__ __launch_bounds__(64, 2) void k_quant(const float* __restrict__ x,
                                                 const float* __restrict__ Wl,
                                                 const float* __restrict__ bl,
                                                 const float* __restrict__ Wr,
                                                 const u64* __restrict__ rm,
                                                 const int* __restrict__ jlist,
                                                 const float* __restrict__ adj,
                                                 float* __restrict__ out) {
    __shared__ float win[34 * 64];      // quantile window (max width 34); GEMV bcast reuse
    __shared__ int   jls[NN];           // slow-path list (statistically unreachable)
    int lane = threadIdx.x;
    int r = blockIdx.x;
    int b = r >> 9, i = r & (NN - 1);
    const float* xb = x + (size_t)b * NN * 64;

    // epoch 1: ONE coalesced load -> candidate list in registers (lane a = cand a)
    int slot = jlist[r * 64 + lane];
    int ct1  = __builtin_amdgcn_readlane(slot, 63);
    int ct   = ct1 + 1;                 // including self at position ct1
    int iw = i >> 6, ib2 = i & 63;

    float qv[6];
    float fr0, fr1, fr2;
    if (ct <= 63) {
        // epoch 2: issue x-gather + rm reverse-check + xi + bl ALL together,
        // then ballot (the single vmcnt drain covers every load in the batch)
        float v32[32], v64o[32];        // NS=64 path uses both halves
        bool big = (ct > 32);
        if (big) { gather_v<32>(xb, slot, ct, v32, lane);
                   gather_v<32>(xb, slot + 0, ct - 32, v64o, lane); }
        else       gather_v<32>(xb, slot, ct, v32, lane);
        // note: for big, v64o holds candidates 32..63 via readlane(slot, a+32)
        if (big) {
            #pragma unroll
            for (int a = 0; a < 32; ++a) {
                int ja = __builtin_amdgcn_readlane(slot, a + 32);
                v64o[a] = (a + 32 < ct) ? xb[(size_t)ja * 64 + lane]
                                        : __builtin_inff();
            }
        }
        float xi = xb[(size_t)i * 64 + lane];
        float bv = bl[lane];
        bool kp = false;
        if (lane < ct) {                // self included: rm[i] bit i is always 0
            u64 rmj = rm[((size_t)(b * NN + slot)) * 8 + iw];
            kp = !((rmj >> ib2) & 1ULL);
        }
        u64 km = __ballot(kp);          // waits the whole batch once
        int deg = __popcll(km);

        float pm = fmaxf((float)deg - 1.0f, 0.0f);
        float pos0 = 0.25f * pm, pos1 = 0.5f * pm, pos2 = 0.75f * pm;
        float l0 = floorf(pos0), l1 = floorf(pos1), l2 = floorf(pos2);
        fr0 = pos0 - l0; fr1 = pos1 - l1; fr2 = pos2 - l2;
        int kks[6] = {(int)l0, (int)ceilf(pos0), (int)l1, (int)ceilf(pos1),
                      (int)l2, (int)ceilf(pos2)};
        int kmin = kks[0], kmax = kks[5];   // width <= 34 for deg <= 64

        if (!big) {
            mask_sort_win<32>(v32, km, win, lane, kmin, kmax);
        } else {
            float v[64];
            #pragma unroll
            for (int a = 0; a < 32; ++a) { v[a] = v32[a]; v[a + 32] = v64o[a]; }
            mask_sort_win<64>(v, km, win, lane, kmin, kmax);
        }
        __syncthreads();
        #pragma unroll
        for (int q = 0; q < 6; ++q) qv[q] = win[(kks[q] - kmin) * 64 + lane];

        // GEMV (epoch 3: W columns) + L2 norm
        __syncthreads();
        win[lane] = 0.25f * (qv[0] * (1.0f - fr0) + qv[1] * fr0)
                  + 0.50f * (qv[2] * (1.0f - fr1) + qv[3] * fr1)
                  + 0.25f * (qv[4] * (1.0f - fr2) + qv[5] * fr2);
        win[64 + lane] = xi;
        __syncthreads();
        float o = bv;
        #pragma unroll
        for (int k = 0; k < 64; ++k)
            o += win[k] * Wl[k * 64 + lane] + win[64 + k] * Wr[k * 64 + lane];

        float ss = o * o;
        #pragma unroll
        for (int off = 32; off >= 1; off >>= 1) ss += __shfl_xor(ss, off);
        out[(size_t)r * 64 + lane] = o / fmaxf(sqrtf(ss), 1e-12f);
        return;
    }

    // ---- slow safe path (ct > 63, statistically unreachable) ----
    {
        const float* arow = adj + (size_t)r * NN;
        u64 lm = (1ULL << lane) - 1ULL;
        int pre2 = 0;
        #pragma unroll
        for (int q = 0; q < 8; ++q) {
            int j = q * 64 + lane;
            u64 mwq   = __ballot((j != i) && (arow[j] > 0.0f));
            u64 rmOwn = rm[(size_t)r * 8 + q];
            bool cand = ((mwq & ~rmOwn) >> lane) & 1ULL;
            u64 rmj2 = 0;
            if (cand) rmj2 = rm[((size_t)(b * NN + j)) * 8 + iw];
            bool kp2 = cand && !((rmj2 >> ib2) & 1ULL);
            u64 kq = __ballot(kp2);
            if (kp2) jls[pre2 + __popcll(kq & lm)] = j;
            pre2 += __popcll(kq);
        }
        if (lane == 0) jls[pre2] = i;
        __syncthreads();
        int deg = pre2 + 1;
        float pm = fmaxf((float)deg - 1.0f, 0.0f);
        float pos0 = 0.25f * pm, pos1 = 0.5f * pm, pos2 = 0.75f * pm;
        float l0 = floorf(pos0), l1 = floorf(pos1), l2 = floorf(pos2);
        fr0 = pos0 - l0; fr1 = pos1 - l1; fr2 = pos2 - l2;
        int kks[6] = {(int)l0, (int)ceilf(pos0), (int)l1, (int)ceilf(pos1),
                      (int)l2, (int)ceilf(pos2)};
        for (int a2 = 0; a2 < deg; ++a2) {
            float v1 = xb[(size_t)jls[a2] * 64 + lane];
            int cl = 0, ce = 0;
            for (int c = 0; c < deg; ++c) {
                float u = xb[(size_t)jls[c] * 64 + lane];
                cl += (u < v1); ce += (u == v1);
            }
            #pragma unroll
            for (int q = 0; q < 6; ++q)
                if (cl <= kks[q] && kks[q] < cl + ce) qv[q] = v1;
        }
        float agg = 0.25f * (qv[0] * (1.0f - fr0) + qv[1] * fr0)
                  + 0.50f * (qv[2] * (1.0f - fr1) + qv[3] * fr1)
                  + 0.25f * (qv[4] * (1.0f - fr2) + qv[5] * fr2);
        float xi = xb[(size_t)i * 64 + lane];
        __syncthreads();
        win[lane] = agg;
        win[64 + lane] = xi;
        __syncthreads();
        float o = bl[lane];
        #pragma unroll
        for (int k = 0; k < 64; ++k)
            o += win[k] * Wl[k * 64 + lane] + win[64 + k] * Wr[k * 64 + lane];
        float ss = o * o;
        #pragma unroll
        for (int off = 32; off >= 1; off >>= 1) ss += __shfl_xor(ss, off);
        out[(size_t)r * 64 + lane] = o / fmaxf(sqrtf(ss), 1e-12f);
    }
}

extern "C" void kernel_launch(void* const* d_in, const int* in_sizes, int n_in,
                              void* d_out, int out_size, void* d_ws, size_t ws_size,
                              hipStream_t stream) {
    const float* x   = (const float*)d_in[0];
    const float* adj = (const float*)d_in[1];
    const float* Wl  = (const float*)d_in[2];
    const float* bl  = (const float*)d_in[3];
    const float* Wr  = (const float*)d_in[4];
    float* out = (float*)d_out;

    int B = in_sizes[0] / (NN * 64);             // 4
    u64* rm    = (u64*)d_ws;                      // B*N*8 u64 = 128 KB
    int* jlist = (int*)(rm + (size_t)B * NN * 8); // B*N*64 int = 512 KB

    k_prep <<<dim3(B * NN), dim3(64), 0, stream>>>(adj, rm, jlist);
    k_quant<<<dim3(B * NN), dim3(64), 0, stream>>>(x, Wl, bl, Wr, rm, jlist, adj, out);
}